// Round 3
// baseline (5257.206 us; speedup 1.0000x reference)
//
#include <hip/hip_runtime.h>
#include <stdint.h>

#define NN 9216     // tokens = 96*96
#define CCH 1024    // channels
#define KK 64       // clusters
#define HP 96       // patch grid
#define SCALE 14
#define HH 1344     // output H=W
#define NUM_ITERS 30
#define TOLV 1e-4

// ---------------- Threefry-2x32-20 block ----------------
__device__ __forceinline__ void tf2x32(unsigned k0, unsigned k1, unsigned& x0, unsigned& x1) {
  unsigned ks2 = k0 ^ k1 ^ 0x1BD11BDAu;
  x0 += k0; x1 += k1;
#define TFR(r) { x0 += x1; x1 = (x1 << r) | (x1 >> (32 - r)); x1 ^= x0; }
  TFR(13) TFR(15) TFR(26) TFR(6)
  x0 += k1; x1 += ks2 + 1u;
  TFR(17) TFR(29) TFR(16) TFR(24)
  x0 += ks2; x1 += k0 + 2u;
  TFR(13) TFR(15) TFR(26) TFR(6)
  x0 += k0; x1 += k1 + 3u;
  TFR(17) TFR(29) TFR(16) TFR(24)
  x0 += k1; x1 += ks2 + 4u;
  TFR(13) TFR(15) TFR(26) TFR(6)
  x0 += ks2; x1 += k0 + 5u;
#undef TFR
}

// jax_threefry_partitionable=True semantics (default since jax 0.4.36):
//   split(key,2): key_i = block(key; x0=hi=0, x1=lo=i), i in {0,1}
//   random_bits(key,32,(N,)): bits[i] = o0 ^ o1 of block(key; 0, i)
// 36 blocks x 256. Also zeroes ssq.
__global__ __launch_bounds__(256) void k_rng(unsigned* bits1, unsigned* bits2, double* ssq) {
  int t = blockIdx.x * 256 + threadIdx.x;      // 0..9215
  unsigned k1a = 0, k1b = 0; tf2x32(0u, 42u, k1a, k1b);   // key1 = block(key0; 0,0)
  unsigned s1a = 0, s1b = 1; tf2x32(0u, 42u, s1a, s1b);   // subkey1 = block(key0; 0,1)
  unsigned s2a = 0, s2b = 1; tf2x32(k1a, k1b, s2a, s2b);  // subkey2 = block(key1; 0,1)
  unsigned o0 = 0, o1 = (unsigned)t;
  tf2x32(s1a, s1b, o0, o1);
  bits1[t] = o0 ^ o1;
  o0 = 0; o1 = (unsigned)t;
  tf2x32(s2a, s2b, o0, o1);
  bits2[t] = o0 ^ o1;
  ssq[t] = 0.0;
}

// stable-sort rank (O(N^2) with LDS broadcast). 36 blocks x 256.
__global__ __launch_bounds__(256) void k_rank(const unsigned* __restrict__ bits,
                                              const unsigned* __restrict__ vals,
                                              unsigned* __restrict__ out_perm) {
  __shared__ __align__(16) unsigned lb[NN];
  int tid = threadIdx.x;
  for (int idx = tid; idx < NN; idx += 256) lb[idx] = bits[idx];
  __syncthreads();
  int i = blockIdx.x * 256 + tid;
  unsigned kb = lb[i];
  const uint4* l4 = reinterpret_cast<const uint4*>(lb);
  int rank = 0;
  for (int jj = 0; jj < NN / 4; ++jj) {
    uint4 v = l4[jj];
    int j = jj * 4;
    rank += (v.x < kb) || (v.x == kb && (j + 0) < i);
    rank += (v.y < kb) || (v.y == kb && (j + 1) < i);
    rank += (v.z < kb) || (v.z == kb && (j + 2) < i);
    rank += (v.w < kb) || (v.w == kb && (j + 3) < i);
  }
  out_perm[rank] = vals ? vals[i] : (unsigned)i;
}

// centers0[k][c] = X[idx[k]][c] (f32, exact). 64 blocks x 256.
__global__ __launch_bounds__(256) void k_gather(const float* __restrict__ F,
                                                const unsigned* __restrict__ perm2,
                                                float* __restrict__ centers) {
  int k = blockIdx.x;
  unsigned n = perm2[k];
  for (int c = threadIdx.x; c < CCH; c += 256)
    centers[k * CCH + c] = F[(size_t)c * NN + n];
}

// exact f64 sum of squares per token. grid (36,16) x 256.
__global__ __launch_bounds__(256) void k_ssq(const float* __restrict__ F, double* __restrict__ ssq) {
  int n = blockIdx.x * 256 + threadIdx.x;
  int c0 = blockIdx.y * 64;
  double acc = 0.0;
#pragma unroll 4
  for (int ci = 0; ci < 64; ++ci) {
    double v = (double)F[(size_t)(c0 + ci) * NN + n];
    acc = fma(v, v, acc);
  }
  atomicAdd(&ssq[n], acc);
}

// correctly-rounded f32 norm per token (mimics f32 reference's norm, center of its noise)
__global__ __launch_bounds__(256) void k_norm32(const double* __restrict__ ssq, float* __restrict__ n32) {
  int n = blockIdx.x * 256 + threadIdx.x;
  n32[n] = (float)sqrt(ssq[n]);
}

// normalize f32 centers -> cnT[c][k] (f32 division); zero sums/counts; done latch. 64 blocks x 256.
__global__ __launch_bounds__(256) void k_prep(const float* __restrict__ centers,
                                              float* __restrict__ cnT,
                                              double* __restrict__ sums,
                                              int* __restrict__ counts,
                                              double* __restrict__ shift,
                                              int* __restrict__ done, int iter) {
  __shared__ double red[256];
  int k = blockIdx.x, tid = threadIdx.x;
  double local = 0.0;
  for (int c = tid; c < CCH; c += 256) {
    double v = (double)centers[k * CCH + c];
    local = fma(v, v, local);
  }
  red[tid] = local; __syncthreads();
  for (int s = 128; s > 0; s >>= 1) { if (tid < s) red[tid] += red[tid + s]; __syncthreads(); }
  float nc = fmaxf((float)sqrt(red[0]), 1e-10f);
  for (int c = tid; c < CCH; c += 256) {
    cnT[(size_t)c * KK + k] = centers[k * CCH + c] / nc;   // f32 division, like reference
    sums[k * CCH + c] = 0.0;
  }
  if (tid == 0) {
    counts[k] = 0;
    if (k == 0) {
      if (iter == 0) { *done = 0; *shift = 0.0; }
      else { double s = *shift; if (s * s < TOLV) *done = 1; *shift = 0.0; }
    }
  }
}

// scores[n][k] = Xn32[n]·cn32[k], exact f64 accumulation of f32-rounded inputs.
// MODE0: argmin over f32 dis=(1-s) -> assign+counts. MODE1: write f32 logitsS[k][n].
// 288 blocks (32 tokens each) x 256 threads.
template <int MODE>
__global__ __launch_bounds__(256) void k_assign(const float* __restrict__ F,
                                                const float* __restrict__ n32,
                                                const float* __restrict__ cnT,
                                                int* __restrict__ assign,
                                                int* __restrict__ counts,
                                                float* __restrict__ logitsS) {
  constexpr int TN = 32, CK = 32;
  __shared__ float As[CK][TN];   // 4 KB
  __shared__ float Bs[CK][KK];   // 8 KB (reused for f32 score tile)
  const int tid = threadIdx.x;
  const int n0 = blockIdx.x * TN;
  const int a_ci = tid >> 3, a_nq = tid & 7;      // A staging
  const int b_ci = tid >> 4, b_kq = tid & 15;     // B staging
  const int nq = tid & 7, kp = tid >> 3;          // compute mapping
  const float* np4 = n32 + n0 + 4 * a_nq;
  float d0 = fmaxf(np4[0], 1e-10f), d1 = fmaxf(np4[1], 1e-10f);
  float d2 = fmaxf(np4[2], 1e-10f), d3 = fmaxf(np4[3], 1e-10f);
  double acc[4][2] = {{0, 0}, {0, 0}, {0, 0}, {0, 0}};
  for (int cc = 0; cc < CCH; cc += CK) {
    float4 v = *(const float4*)(F + (size_t)(cc + a_ci) * NN + n0 + 4 * a_nq);
    As[a_ci][4 * a_nq + 0] = v.x / d0;   // f32 division: Xn rounded like reference
    As[a_ci][4 * a_nq + 1] = v.y / d1;
    As[a_ci][4 * a_nq + 2] = v.z / d2;
    As[a_ci][4 * a_nq + 3] = v.w / d3;
#pragma unroll
    for (int r = 0; r < 2; ++r) {
      int ci = b_ci + 16 * r;
      float4 p = *(const float4*)(cnT + (size_t)(cc + ci) * KK + 4 * b_kq);
      Bs[ci][4 * b_kq + 0] = p.x; Bs[ci][4 * b_kq + 1] = p.y;
      Bs[ci][4 * b_kq + 2] = p.z; Bs[ci][4 * b_kq + 3] = p.w;
    }
    __syncthreads();
#pragma unroll 8
    for (int ci = 0; ci < CK; ++ci) {
      double b0 = (double)Bs[ci][2 * kp + 0], b1 = (double)Bs[ci][2 * kp + 1];
      double a0 = (double)As[ci][4 * nq + 0], a1 = (double)As[ci][4 * nq + 1];
      double a2 = (double)As[ci][4 * nq + 2], a3 = (double)As[ci][4 * nq + 3];
      acc[0][0] = fma(a0, b0, acc[0][0]); acc[0][1] = fma(a0, b1, acc[0][1]);
      acc[1][0] = fma(a1, b0, acc[1][0]); acc[1][1] = fma(a1, b1, acc[1][1]);
      acc[2][0] = fma(a2, b0, acc[2][0]); acc[2][1] = fma(a2, b1, acc[2][1]);
      acc[3][0] = fma(a3, b0, acc[3][0]); acc[3][1] = fma(a3, b1, acc[3][1]);
    }
    __syncthreads();
  }
  float* Sl = &Bs[0][0];   // [TN][KK] f32 scores
#pragma unroll
  for (int r = 0; r < 4; ++r) {
    Sl[(4 * nq + r) * KK + 2 * kp + 0] = (float)acc[r][0];
    Sl[(4 * nq + r) * KK + 2 * kp + 1] = (float)acc[r][1];
  }
  __syncthreads();
  if (MODE == 0) {
    if (tid < TN) {
      const float* row = &Sl[tid * KK];
      float best = 1.0f - row[0]; int bk = 0;   // f32 "1 - sim": coarse ties resolve to first index
      for (int k = 1; k < KK; ++k) { float d = 1.0f - row[k]; if (d < best) { best = d; bk = k; } }
      assign[n0 + tid] = bk;
      atomicAdd(&counts[bk], 1);
    }
  } else {
    for (int idx = tid; idx < TN * KK; idx += 256) {
      int k = idx >> 5, nj = idx & 31;
      logitsS[(size_t)k * NN + n0 + nj] = Sl[nj * KK + k];
    }
  }
}

// per-channel exact f64 segment sum of UNNORMALIZED X. 1024 blocks x 256.
__global__ __launch_bounds__(256) void k_segsum(const float* __restrict__ F,
                                                const int* __restrict__ assign,
                                                double* __restrict__ sums) {
  __shared__ double bins[KK];
  int c = blockIdx.x, tid = threadIdx.x;
  if (tid < KK) bins[tid] = 0.0;
  __syncthreads();
  for (int n = tid; n < NN; n += 256) {
    int a = assign[n];
    double v = (double)F[(size_t)c * NN + n];
    atomicAdd(&bins[a], v);
  }
  __syncthreads();
  if (tid < KK) sums[(size_t)tid * CCH + c] = bins[tid];
}

// center update (f32 stored, correctly-rounded mean) + shift. 64 blocks x 256.
__global__ __launch_bounds__(256) void k_update(float* __restrict__ centers,
                                                const double* __restrict__ sums,
                                                const int* __restrict__ counts,
                                                double* __restrict__ shift,
                                                const int* __restrict__ done) {
  if (*done) return;
  __shared__ double red[256];
  int k = blockIdx.x, tid = threadIdx.x;
  int cnt = counts[k];
  double local = 0.0;
  for (int c = tid; c < CCH; c += 256) {
    float old = centers[k * CCH + c];
    float nc = (cnt > 0) ? (float)(sums[k * CCH + c] / (double)cnt) : old;
    double d = (double)nc - (double)old;
    local = fma(d, d, local);
    centers[k * CCH + c] = nc;
  }
  red[tid] = local; __syncthreads();
  for (int s = 128; s > 0; s >>= 1) { if (tid < s) red[tid] += red[tid + s]; __syncthreads(); }
  if (tid == 0) atomicAdd(shift, sqrt(red[0]));
}

// fused bilinear x14 upsample + argmax, all-f32 mimicking jax resize. grid (96,96) x 256.
__global__ __launch_bounds__(256) void k_upsample(const float* __restrict__ logitsS,
                                                  float* __restrict__ out) {
  __shared__ float P[KK * 9];
  int tx = blockIdx.x, ty = blockIdx.y, tid = threadIdx.x;
  for (int idx = tid; idx < KK * 9; idx += 256) {
    int k = idx / 9, p = idx % 9;
    int iy = min(max(ty - 1 + p / 3, 0), HP - 1);
    int ix = min(max(tx - 1 + p % 3, 0), HP - 1);
    P[idx] = logitsS[(size_t)k * NN + iy * HP + ix];
  }
  __syncthreads();
  if (tid < SCALE * SCALE) {
    int ry = tid / SCALE, rx = tid % SCALE;
    int oy = ty * SCALE + ry, ox = tx * SCALE + rx;
    const float inv = 1.0f / 14.0f;
    float s_y = ((float)oy + 0.5f) * inv - 0.5f;
    float fy = floorf(s_y);
    float wy1 = s_y - fy, wy0 = 1.0f - wy1;
    int py0 = (int)fy - ty + 1;
    if ((ty == 0 && py0 == 0) || (ty == HP - 1 && py0 == 1)) { wy0 = 1.0f; wy1 = 0.0f; } // edge renorm -> weight 1
    float s_x = ((float)ox + 0.5f) * inv - 0.5f;
    float fx = floorf(s_x);
    float wx1 = s_x - fx, wx0 = 1.0f - wx1;
    int px0 = (int)fx - tx + 1;
    if ((tx == 0 && px0 == 0) || (tx == HP - 1 && px0 == 1)) { wx0 = 1.0f; wx1 = 0.0f; }
    float* outL = out + (size_t)HH * HH;
    size_t opix = (size_t)oy * HH + ox;
    float best = 0.0f; int bk = 0;
    for (int k = 0; k < KK; ++k) {
      const float* p = &P[k * 9];
      float t0 = fmaf(wy1, p[(py0 + 1) * 3 + px0],     wy0 * p[py0 * 3 + px0]);
      float t1 = fmaf(wy1, p[(py0 + 1) * 3 + px0 + 1], wy0 * p[py0 * 3 + px0 + 1]);
      float v  = fmaf(wx1, t1, wx0 * t0);
      outL[(size_t)k * (HH * HH) + opix] = v;
      if (k == 0 || v > best) { best = v; bk = k; }
    }
    out[opix] = (float)bk;
  }
}

extern "C" void kernel_launch(void* const* d_in, const int* in_sizes, int n_in,
                              void* d_out, int out_size, void* d_ws, size_t ws_size,
                              hipStream_t stream) {
  const float* F = (const float*)d_in[0];
  float* out = (float*)d_out;
  char* ws = (char*)d_ws;
  // workspace layout (bytes)
  double*   ssq     = (double*)(ws + 0);         // 9216 d
  float*    n32     = (float*)(ws + 73728);      // 9216 f
  float*    centers = (float*)(ws + 110592);     // 64*1024 f
  float*    cnT     = (float*)(ws + 372736);     // 1024*64 f
  double*   sums    = (double*)(ws + 634880);    // 64*1024 d
  float*    logitsS = (float*)(ws + 1159168);    // 64*9216 f
  double*   shift   = (double*)(ws + 3518464);   // 1 d
  unsigned* bits1   = (unsigned*)(ws + 3518472);
  unsigned* bits2   = (unsigned*)(ws + 3555336);
  unsigned* perm1   = (unsigned*)(ws + 3592200);
  unsigned* perm2   = (unsigned*)(ws + 3629064);
  int*      assign  = (int*)(ws + 3665928);
  int*      counts  = (int*)(ws + 3702792);
  int*      done    = (int*)(ws + 3703048);

  k_rng<<<36, 256, 0, stream>>>(bits1, bits2, ssq);
  k_rank<<<36, 256, 0, stream>>>(bits1, nullptr, perm1);
  k_rank<<<36, 256, 0, stream>>>(bits2, perm1, perm2);
  k_gather<<<64, 256, 0, stream>>>(F, perm2, centers);
  k_ssq<<<dim3(36, 16), 256, 0, stream>>>(F, ssq);
  k_norm32<<<36, 256, 0, stream>>>(ssq, n32);

  for (int it = 0; it <= NUM_ITERS; ++it) {
    k_prep<<<64, 256, 0, stream>>>(centers, cnT, sums, counts, shift, done, it);
    if (it == NUM_ITERS) break;
    k_assign<0><<<288, 256, 0, stream>>>(F, n32, cnT, assign, counts, logitsS);
    k_segsum<<<1024, 256, 0, stream>>>(F, assign, sums);
    k_update<<<64, 256, 0, stream>>>(centers, sums, counts, shift, done);
  }
  k_assign<1><<<288, 256, 0, stream>>>(F, n32, cnT, assign, counts, logitsS);
  k_upsample<<<dim3(96, 96), 256, 0, stream>>>(logitsS, out);
}